// Round 4
// baseline (169.305 us; speedup 1.0000x reference)
//
#include <hip/hip_runtime.h>

namespace {

constexpr int T_LEN = 512;
constexpr int XS    = 516;   // padded floats per x-row in LDS

typedef _Float16 half4  __attribute__((ext_vector_type(4)));
typedef float    f32x4v __attribute__((ext_vector_type(4)));
typedef unsigned uint2v __attribute__((ext_vector_type(2)));

#define MFMA16(a, b, c) __builtin_amdgcn_mfma_f32_16x16x16f16((a), (b), (c), 0, 0, 0)

__device__ __forceinline__ half4 cvt_h4(f32x4v a) {
    uint2v u;
    u.x = __builtin_bit_cast(unsigned, __builtin_amdgcn_cvt_pkrtz(a[0], a[1]));
    u.y = __builtin_bit_cast(unsigned, __builtin_amdgcn_cvt_pkrtz(a[2], a[3]));
    return __builtin_bit_cast(half4, u);
}

// k16 A-fragment: lane (g,b16) holds W[row][k0 + 4g .. +3], scaled.
__device__ __forceinline__ half4 load_q(const float* __restrict__ W,
                                        int row, int k0, float s) {
    f32x4v v = *reinterpret_cast<const f32x4v*>(W + row * 64 + k0);
    return cvt_h4(v * s);
}

// a holds 2*preact; tanh(y) = 1 - 2/(exp(2y)+1), robust at +-inf.
__device__ __forceinline__ void tanh4(f32x4v &a) {
#pragma unroll
    for (int q = 0; q < 4; ++q) {
        float e = __expf(a[q]);
        a[q] = 1.0f - 2.0f * __builtin_amdgcn_rcpf(e + 1.0f);
    }
}

// XOR-swizzled address into a [16][64]-half exchange buffer.
// Logical element (batch b, hidden row r0), r0 always even (granularity >= 2).
// dword index d = 32b + r0/2, swizzled d ^= (b&7)<<2: writes at floor,
// reads <= 2x floor (analytically; no 8/16-way conflicts).
__device__ __forceinline__ _Float16* swzp(_Float16* base, int b, int r0) {
    int d = (b << 5) + (r0 >> 1);
    d ^= (b & 7) << 2;
    return base + (d << 1);
}
__device__ __forceinline__ const _Float16* swzc(const _Float16* base, int b, int r0) {
    int d = (b << 5) + (r0 >> 1);
    d ^= (b & 7) << 2;
    return base + (d << 1);
}

__global__ __launch_bounds__(256, 1)
void rnn_k16_kernel(const float* __restrict__ x,
                    const float* __restrict__ Wih0,
                    const float* __restrict__ Whh0,
                    const float* __restrict__ bih0,
                    const float* __restrict__ bhh0,
                    const float* __restrict__ Wih1,
                    const float* __restrict__ Whh1,
                    const float* __restrict__ bih1,
                    const float* __restrict__ bhh1,
                    const float* __restrict__ fc1W,
                    const float* __restrict__ fc1b,
                    const float* __restrict__ fc2W,
                    const float* __restrict__ fc2b,
                    float* __restrict__ out)
{
    const int tid    = threadIdx.x;
    const int wv     = tid >> 6;        // wave owns hidden rows 16wv..16wv+15
    const int lane   = tid & 63;
    const int g      = lane >> 4;
    const int b16    = lane & 15;       // batch within 16-batch tile
    const int batch0 = blockIdx.x * 16;

    __shared__ float    sx[16 * XS];
    __shared__ _Float16 sh1[2][16 * 64];   // h1 exchange, ping-pong, swizzled
    __shared__ _Float16 sh2[2][16 * 64];   // h2 exchange
    __shared__ float    pf[4][16];

    // ---- stage x tile (coalesced float4) ----
    {
        const float* gx = x + (size_t)batch0 * T_LEN;
#pragma unroll
        for (int c = 0; c < 8; ++c) {
            int idx = tid + c * 256;
            int r = idx >> 7, c4 = idx & 127;
            f32x4v v = *reinterpret_cast<const f32x4v*>(gx + r * T_LEN + c4 * 4);
            *reinterpret_cast<f32x4v*>(&sx[r * XS + c4 * 4]) = v;
        }
    }

    // ---- per-wave k16 weight fragments (x2 folds tanh's 2y) ----
    const int row = 16 * wv + b16;
    const int q0 = (wv + 1) & 3, q1 = (wv + 2) & 3, q2 = (wv + 3) & 3;

    const half4 A0own = load_q(Whh0, row, 16 * wv + 4 * g, 2.0f);
    const half4 A0o0  = load_q(Whh0, row, 16 * q0 + 4 * g, 2.0f);
    const half4 A0o1  = load_q(Whh0, row, 16 * q1 + 4 * g, 2.0f);
    const half4 A0o2  = load_q(Whh0, row, 16 * q2 + 4 * g, 2.0f);
    const half4 I1own = load_q(Wih1, row, 16 * wv + 4 * g, 2.0f);
    const half4 I1o0  = load_q(Wih1, row, 16 * q0 + 4 * g, 2.0f);
    const half4 I1o1  = load_q(Wih1, row, 16 * q1 + 4 * g, 2.0f);
    const half4 I1o2  = load_q(Wih1, row, 16 * q2 + 4 * g, 2.0f);
    const half4 H1own = load_q(Whh1, row, 16 * wv + 4 * g, 2.0f);
    const half4 H1o0  = load_q(Whh1, row, 16 * q0 + 4 * g, 2.0f);
    const half4 H1o1  = load_q(Whh1, row, 16 * q1 + 4 * g, 2.0f);
    const half4 H1o2  = load_q(Whh1, row, 16 * q2 + 4 * g, 2.0f);

    f32x4v bb0, bb1, wx2;
#pragma unroll
    for (int q = 0; q < 4; ++q) {
        const int o = 16 * wv + 4 * g + q;     // D-layout row this lane owns
        bb0[q] = 2.0f * (bih0[o] + bhh0[o]);
        bb1[q] = 2.0f * (bih1[o] + bhh1[o]);
        wx2[q] = 2.0f * Wih0[o];
    }
    const int ro = 16 * wv + 4 * g;            // own publish row offset

    __syncthreads();                           // x staged

    f32x4v p0, p1;                             // early own-quarter partials
    // ---- peel k=0: h1(0) = tanh(2(wx*x0+b0)); h2(-1)=0 ----
    {
        const float x0 = sx[b16 * XS + 0];
        const float x1 = sx[b16 * XS + 1];
        f32x4v a0 = wx2 * x0 + bb0;
        tanh4(a0);
        half4 b1own = cvt_h4(a0);
        *reinterpret_cast<half4*>(swzp(sh1[0], b16, ro)) = b1own;
        half4 z4 = {};
        *reinterpret_cast<half4*>(swzp(sh2[0], b16, ro)) = z4;
        p0 = MFMA16(A0own, b1own, wx2 * x1 + bb0);   // partial for h1(1)
        p1 = MFMA16(I1own, b1own, bb1);              // partial for h2(0); H1 term = 0
        __syncthreads();
    }

    // ---- main loop: iter k computes h1(k) and h2(k-1) ----
#pragma unroll 2
    for (int k = 1; k < T_LEN; ++k) {
        const int s  = k & 1;
        const int rd = s ^ 1;
        const _Float16* r1 = sh1[rd];
        const _Float16* r2 = sh2[rd];

        // foreign-quarter fragments of h1(k-1), h2(k-2)
        half4 f10 = *reinterpret_cast<const half4*>(swzc(r1, b16, 16 * q0 + 4 * g));
        half4 f11 = *reinterpret_cast<const half4*>(swzc(r1, b16, 16 * q1 + 4 * g));
        half4 f12 = *reinterpret_cast<const half4*>(swzc(r1, b16, 16 * q2 + 4 * g));
        half4 f20 = *reinterpret_cast<const half4*>(swzc(r2, b16, 16 * q0 + 4 * g));
        half4 f21 = *reinterpret_cast<const half4*>(swzc(r2, b16, 16 * q1 + 4 * g));
        half4 f22 = *reinterpret_cast<const half4*>(swzc(r2, b16, 16 * q2 + 4 * g));
        const float xk1 = sx[b16 * XS + k + 1];   // x(k+1) for next early partial

        // layer0: a0 = p0 (own+bias+x) + foreign quarters, balanced tree
        f32x4v zz = {};
        f32x4v u  = MFMA16(A0o0, f10, p0);
        f32x4v v  = MFMA16(A0o1, f11, zz);
        u = MFMA16(A0o2, f12, u);
        f32x4v a0 = u + v;
        tanh4(a0);
        half4 b1own = cvt_h4(a0);                 // h1(k) own rows
        *reinterpret_cast<half4*>(swzp(sh1[s], b16, ro)) = b1own;

        // layer1: a1 = p1 (own h1,h2 parts + bias) + 6 foreign quarters
        f32x4v u1 = MFMA16(I1o0, f10, p1);
        f32x4v v1 = MFMA16(I1o1, f11, zz);
        u1 = MFMA16(I1o2, f12, u1);
        v1 = MFMA16(H1o0, f20, v1);
        u1 = MFMA16(H1o1, f21, u1);
        v1 = MFMA16(H1o2, f22, v1);
        f32x4v a1 = u1 + v1;
        tanh4(a1);
        half4 b2own = cvt_h4(a1);                 // h2(k-1) own rows
        *reinterpret_cast<half4*>(swzp(sh2[s], b16, ro)) = b2own;

        // early own-quarter partials for iteration k+1
        p0 = MFMA16(A0own, b1own, wx2 * xk1 + bb0);
        p1 = MFMA16(I1own, b1own, bb1);
        p1 = MFMA16(H1own, b2own, p1);

        __syncthreads();
    }

    // ---- epilogue step: h2(511) from h1(511), h2(510) (buffers s=1) ----
    half4 b2fin;
    {
        const _Float16* r1 = sh1[1];
        const _Float16* r2 = sh2[1];
        half4 f10 = *reinterpret_cast<const half4*>(swzc(r1, b16, 16 * q0 + 4 * g));
        half4 f11 = *reinterpret_cast<const half4*>(swzc(r1, b16, 16 * q1 + 4 * g));
        half4 f12 = *reinterpret_cast<const half4*>(swzc(r1, b16, 16 * q2 + 4 * g));
        half4 f20 = *reinterpret_cast<const half4*>(swzc(r2, b16, 16 * q0 + 4 * g));
        half4 f21 = *reinterpret_cast<const half4*>(swzc(r2, b16, 16 * q1 + 4 * g));
        half4 f22 = *reinterpret_cast<const half4*>(swzc(r2, b16, 16 * q2 + 4 * g));
        f32x4v zz = {};
        f32x4v u1 = MFMA16(I1o0, f10, p1);
        f32x4v v1 = MFMA16(I1o1, f11, zz);
        u1 = MFMA16(I1o2, f12, u1);
        v1 = MFMA16(H1o0, f20, v1);
        u1 = MFMA16(H1o1, f21, u1);
        v1 = MFMA16(H1o2, f22, v1);
        f32x4v a1 = u1 + v1;
        tanh4(a1);
        b2fin = cvt_h4(a1);
        *reinterpret_cast<half4*>(swzp(sh2[0], b16, ro)) = b2fin;  // h2(511)
        __syncthreads();
    }

    // ---- fc1 (k16 tree) + relu + fc2 dot ----
    {
        const half4 Fown = load_q(fc1W, row, 16 * wv + 4 * g, 1.0f);
        const half4 Fo0  = load_q(fc1W, row, 16 * q0 + 4 * g, 1.0f);
        const half4 Fo1  = load_q(fc1W, row, 16 * q1 + 4 * g, 1.0f);
        const half4 Fo2  = load_q(fc1W, row, 16 * q2 + 4 * g, 1.0f);
        const _Float16* r2 = sh2[0];
        half4 e0 = *reinterpret_cast<const half4*>(swzc(r2, b16, 16 * q0 + 4 * g));
        half4 e1 = *reinterpret_cast<const half4*>(swzc(r2, b16, 16 * q1 + 4 * g));
        half4 e2 = *reinterpret_cast<const half4*>(swzc(r2, b16, 16 * q2 + 4 * g));

        f32x4v zb;
#pragma unroll
        for (int q = 0; q < 4; ++q) zb[q] = fc1b[16 * wv + 4 * g + q];
        f32x4v zz = {};
        f32x4v zu = MFMA16(Fown, b2fin, zb);
        f32x4v zv = MFMA16(Fo0, e0, zz);
        zu = MFMA16(Fo1, e1, zu);
        zv = MFMA16(Fo2, e2, zv);
        f32x4v zf = zu + zv;

        float pacc = 0.0f;
#pragma unroll
        for (int q = 0; q < 4; ++q)
            pacc += fmaxf(zf[q], 0.0f) * fc2W[16 * wv + 4 * g + q];
        pacc += __shfl_xor(pacc, 16);
        pacc += __shfl_xor(pacc, 32);
        if (lane < 16) pf[wv][lane] = pacc;
    }
    __syncthreads();
    if (tid < 16)
        out[batch0 + tid] = pf[0][tid] + pf[1][tid] + pf[2][tid] + pf[3][tid]
                          + fc2b[0];
}

} // namespace

extern "C" void kernel_launch(void* const* d_in, const int* in_sizes, int n_in,
                              void* d_out, int out_size, void* d_ws, size_t ws_size,
                              hipStream_t stream) {
    (void)n_in; (void)out_size; (void)d_ws; (void)ws_size;
    const float* x    = (const float*)d_in[0];
    const float* Wih0 = (const float*)d_in[1];
    const float* Whh0 = (const float*)d_in[2];
    const float* bih0 = (const float*)d_in[3];
    const float* bhh0 = (const float*)d_in[4];
    const float* Wih1 = (const float*)d_in[5];
    const float* Whh1 = (const float*)d_in[6];
    const float* bih1 = (const float*)d_in[7];
    const float* bhh1 = (const float*)d_in[8];
    const float* fc1W = (const float*)d_in[9];
    const float* fc1b = (const float*)d_in[10];
    const float* fc2W = (const float*)d_in[11];
    const float* fc2b = (const float*)d_in[12];
    float* out = (float*)d_out;

    const int B = in_sizes[0] / T_LEN;      // 4096
    dim3 grid(B / 16), block(256);
    rnn_k16_kernel<<<grid, block, 0, stream>>>(
        x, Wih0, Whh0, bih0, bhh0, Wih1, Whh1, bih1, bhh1,
        fc1W, fc1b, fc2W, fc2b, out);
}